// Round 3
// baseline (291.319 us; speedup 1.0000x reference)
//
#include <hip/hip_runtime.h>
#include <cstdint>
#include <cstddef>

#define N_DIM 4096
#define M_DIM 4096
#define D_DIM 4096

typedef unsigned short u16;
typedef u16   u16x8 __attribute__((ext_vector_type(8)));
typedef short s16x8 __attribute__((ext_vector_type(8)));   // 8 bf16 (4 VGPRs)
typedef float f32x4 __attribute__((ext_vector_type(4)));   // MFMA accumulator

// ---------- fp32 -> bf16 (RTNE) ----------
__device__ __forceinline__ u16 f2bf(float f) {
    union { float f; uint32_t u; } v; v.f = f;
    uint32_t u = v.u;
    uint32_t r = u + 0x7fffu + ((u >> 16) & 1u);
    return (u16)(r >> 16);
}

__global__ __launch_bounds__(256) void convert_both(
    const float* __restrict__ A, const float* __restrict__ B,
    u16* __restrict__ Oa, u16* __restrict__ Ob) {
    const size_t nv8 = (size_t)N_DIM * D_DIM / 8;
    size_t gid = (size_t)blockIdx.x * blockDim.x + threadIdx.x;
    size_t stride = (size_t)gridDim.x * blockDim.x;
    for (size_t i = gid; i < nv8; i += stride) {
        float4 v0 = ((const float4*)A)[2 * i];
        float4 v1 = ((const float4*)A)[2 * i + 1];
        u16x8 o;
        o[0] = f2bf(v0.x); o[1] = f2bf(v0.y); o[2] = f2bf(v0.z); o[3] = f2bf(v0.w);
        o[4] = f2bf(v1.x); o[5] = f2bf(v1.y); o[6] = f2bf(v1.z); o[7] = f2bf(v1.w);
        ((u16x8*)Oa)[i] = o;
    }
    for (size_t i = gid; i < nv8; i += stride) {
        float4 v0 = ((const float4*)B)[2 * i];
        float4 v1 = ((const float4*)B)[2 * i + 1];
        u16x8 o;
        o[0] = f2bf(v0.x); o[1] = f2bf(v0.y); o[2] = f2bf(v0.z); o[3] = f2bf(v0.w);
        o[4] = f2bf(v1.x); o[5] = f2bf(v1.y); o[6] = f2bf(v1.z); o[7] = f2bf(v1.w);
        ((u16x8*)Ob)[i] = o;
    }
}

// ---------- async global->LDS, 16B/lane, wave-uniform LDS base ----------
__device__ __forceinline__ void g2l16(const u16* g, u16* l) {
    __builtin_amdgcn_global_load_lds(
        (const __attribute__((address_space(1))) void*)g,
        (__attribute__((address_space(3))) void*)l,
        16, 0, 0);
}

// ---- Geometry ----
// Tile 128x256, BK=32, grid 512 = 2 blocks/CU (LDS 72 KB/block).
// Triple-buffered regions: A[k] = 128x32 bf16 (8 KB), B[k] = 256x32 (16 KB).
// Row = 64 B = 4 chunks of 16 B; XOR swizzle: logical chunk c of row r at
// physical chunk c ^ ((r>>1)&3) (verified 0 bank conflicts in rounds 0-2).
// Inverse swizzle applied on the GLOBAL source chunk (LDS dest of
// global_load_lds must stay wave-uniform-base + lane*16).

// LDS -> register MFMA fragment offset (in u16 units), thread-invariant
__device__ __forceinline__ int frag_off(int row, int cbq) {
    return row * 32 + (cbq ^ ((row >> 1) & 3)) * 8;
}

// One phase = one K-tile: 8 ds_read_b128, 3 global_load_lds (prefetch t+2),
// barrier, lgkmcnt(0), 16 MFMA under setprio, vmcnt(3) (never 0), barrier.
// Race-freedom: region staged at phase t was last ds-read at phase t-1 and
// those reads drain at t-1's lgkmcnt(0), before t-1's end barrier, which all
// waves pass before t's stage issues. vmcnt(3) at end of phase t waits for
// tile t+1's 3 loads (per-wave wait BEFORE a barrier => after the barrier all
// waves' shares have landed), leaving tile t+2's 3 loads in flight.
#define PHASE(KA, KB, SGA, SGB, SLA, SLB)                                     \
  {                                                                           \
    s16x8 af[4], bfr[4];                                                      \
    _Pragma("unroll")                                                         \
    for (int i = 0; i < 4; ++i) af[i]  = *(const s16x8*)&(KA)[aoff[i]];       \
    _Pragma("unroll")                                                         \
    for (int j = 0; j < 4; ++j) bfr[j] = *(const s16x8*)&(KB)[boff[j]];       \
    g2l16((SGA) + offA,  (SLA) + wave * 512);                                 \
    g2l16((SGB) + offB0, (SLB) + wave * 512);                                 \
    g2l16((SGB) + offB1, (SLB) + (8 + wave) * 512);                           \
    __builtin_amdgcn_s_barrier();                                             \
    asm volatile("s_waitcnt lgkmcnt(0)");                                     \
    __builtin_amdgcn_s_setprio(1);                                            \
    _Pragma("unroll")                                                         \
    for (int i = 0; i < 4; ++i) {                                             \
      _Pragma("unroll")                                                       \
      for (int j = 0; j < 4; ++j)                                             \
        acc[i][j] = __builtin_amdgcn_mfma_f32_16x16x32_bf16(                  \
            af[i], bfr[j], acc[i][j], 0, 0, 0);                               \
    }                                                                         \
    __builtin_amdgcn_s_setprio(0);                                            \
    asm volatile("s_waitcnt vmcnt(3)");                                       \
    __builtin_amdgcn_s_barrier();                                             \
  }

__global__ __launch_bounds__(512, 4) void gemm_bt_bf16(
    const u16* __restrict__ A, const u16* __restrict__ B, float* __restrict__ C) {
    __shared__ __align__(16) u16 sm[36864];   // 72 KB -> 2 blocks/CU
    u16* sA0 = sm;           u16* sA1 = sm + 4096;   u16* sA2 = sm + 8192;
    u16* sB0 = sm + 12288;   u16* sB1 = sm + 20480;  u16* sB2 = sm + 28672;

    const int tid   = threadIdx.x;
    const int lane  = tid & 63;
    const int wave  = tid >> 6;       // 0..7
    const int waveM = wave >> 2;      // 0..1  (64-row band of 128)
    const int waveN = wave & 3;       // 0..3  (64-col band of 256)
    const int fr    = lane & 15;      // frag row
    const int cbq   = lane >> 4;      // frag k-chunk (0..3)

    // XCD swizzle: 512 blocks over a 32(Y,128-row) x 16(X,256-col) tile grid;
    // each XCD owns a contiguous 8x8 tile rectangle (bijective: 8*64=512).
    const int lin  = blockIdx.x;
    const int xcd  = lin & 7;
    const int j    = lin >> 3;                    // 0..63
    const int tileY = (xcd >> 1) * 8 + (j & 7);   // 0..31
    const int tileX = (xcd & 1) * 8 + (j >> 3);   // 0..15
    const int rowBase = tileY * 128;
    const int colBase = tileX * 256;

    const u16* Abase = A + (size_t)rowBase * D_DIM;
    const u16* Bbase = B + (size_t)colBase * D_DIM;

    // Thread-invariant staging offsets (global source, inverse-swizzled chunk)
    const int sa  = wave * 64 + lane;             // A chunk slot 0..511
    const size_t offA = (size_t)(sa >> 2) * D_DIM + (size_t)(((sa & 3) ^ ((sa >> 3) & 3)) * 8);
    const int sb0 = wave * 64 + lane;             // B slot, jj=0 (0..511)
    const int sb1 = (8 + wave) * 64 + lane;       // B slot, jj=1 (512..1023)
    const size_t offB0 = (size_t)(sb0 >> 2) * D_DIM + (size_t)(((sb0 & 3) ^ ((sb0 >> 3) & 3)) * 8);
    const size_t offB1 = (size_t)(sb1 >> 2) * D_DIM + (size_t)(((sb1 & 3) ^ ((sb1 >> 3) & 3)) * 8);

    // Thread-invariant fragment read offsets (u16 units)
    int aoff[4], boff[4];
    #pragma unroll
    for (int i = 0; i < 4; ++i) aoff[i] = frag_off(waveM * 64 + i * 16 + fr, cbq);
    #pragma unroll
    for (int jj = 0; jj < 4; ++jj) boff[jj] = frag_off(waveN * 64 + jj * 16 + fr, cbq);

    f32x4 acc[4][4] = {};

    // Prologue: stage tiles 0,1 (6 loads/thread); vmcnt(3) -> tile 0 landed,
    // tile 1's 3 loads remain in flight (steady-state entry condition).
    g2l16(Abase + offA,  sA0 + wave * 512);
    g2l16(Bbase + offB0, sB0 + wave * 512);
    g2l16(Bbase + offB1, sB0 + (8 + wave) * 512);
    g2l16(Abase + 32 + offA,  sA1 + wave * 512);
    g2l16(Bbase + 32 + offB0, sB1 + wave * 512);
    g2l16(Bbase + 32 + offB1, sB1 + (8 + wave) * 512);
    asm volatile("s_waitcnt vmcnt(3)");
    __builtin_amdgcn_s_barrier();

    // 128 K-tiles; phase t reads buf[t%3], stages t+2 into buf[(t+2)%3].
    #pragma unroll 1
    for (int t = 0; t < 126; t += 3) {
        const u16* As2 = Abase + (t + 2) * 32;
        const u16* Bs2 = Bbase + (t + 2) * 32;
        PHASE(sA0, sB0, As2,      Bs2,      sA2, sB2)
        PHASE(sA1, sB1, As2 + 32, Bs2 + 32, sA0, sB0)
        PHASE(sA2, sB2, As2 + 64, Bs2 + 64, sA1, sB1)
    }
    // Tail: t=126 (buf0), t=127 (buf1); clamped re-stages keep vmcnt counts
    // consistent (written regions are never read again).
    {
        const u16* Ax = Abase + 127 * 32;
        const u16* Bx = Bbase + 127 * 32;
        PHASE(sA0, sB0, Ax, Bx, sA2, sB2)
        PHASE(sA1, sB1, Ax, Bx, sA0, sB0)
    }

    // Epilogue. C/D layout (verified m89/m91): col = lane&15, row = (lane>>4)*4 + reg
    #pragma unroll
    for (int mt = 0; mt < 4; ++mt) {
        int gr0 = rowBase + waveM * 64 + mt * 16 + (lane >> 4) * 4;
        #pragma unroll
        for (int nt = 0; nt < 4; ++nt) {
            int gc = colBase + waveN * 64 + nt * 16 + (lane & 15);
            #pragma unroll
            for (int r = 0; r < 4; ++r)
                C[(size_t)(gr0 + r) * M_DIM + gc] = acc[mt][nt][r];
        }
    }
}

extern "C" void kernel_launch(void* const* d_in, const int* in_sizes, int n_in,
                              void* d_out, int out_size, void* d_ws, size_t ws_size,
                              hipStream_t stream) {
    const float* A32 = (const float*)d_in[0];
    const float* B32 = (const float*)d_in[1];
    float* C = (float*)d_out;

    u16* Abf = (u16*)d_ws;
    u16* Bbf = Abf + (size_t)N_DIM * D_DIM;

    convert_both<<<4096, 256, 0, stream>>>(A32, B32, Abf, Bbf);
    gemm_bt_bf16<<<512, 512, 0, stream>>>(Abf, Bbf, C);
}

// Round 4
// 281.935 us; speedup vs baseline: 1.0333x; 1.0333x over previous
//
#include <hip/hip_runtime.h>
#include <cstdint>
#include <cstddef>

#define N_DIM 4096
#define M_DIM 4096
#define D_DIM 4096

typedef unsigned short u16;
typedef u16   u16x8 __attribute__((ext_vector_type(8)));
typedef short s16x8 __attribute__((ext_vector_type(8)));   // 8 bf16 (4 VGPRs)
typedef float f32x4 __attribute__((ext_vector_type(4)));   // MFMA accumulator

// ---------- fp32 -> bf16 (RTNE) ----------
__device__ __forceinline__ u16 f2bf(float f) {
    union { float f; uint32_t u; } v; v.f = f;
    uint32_t u = v.u;
    uint32_t r = u + 0x7fffu + ((u >> 16) & 1u);
    return (u16)(r >> 16);
}

__global__ __launch_bounds__(256) void convert_both(
    const float* __restrict__ A, const float* __restrict__ B,
    u16* __restrict__ Oa, u16* __restrict__ Ob) {
    const size_t nv8 = (size_t)N_DIM * D_DIM / 8;
    size_t gid = (size_t)blockIdx.x * blockDim.x + threadIdx.x;
    size_t stride = (size_t)gridDim.x * blockDim.x;
    for (size_t i = gid; i < nv8; i += stride) {
        float4 v0 = ((const float4*)A)[2 * i];
        float4 v1 = ((const float4*)A)[2 * i + 1];
        u16x8 o;
        o[0] = f2bf(v0.x); o[1] = f2bf(v0.y); o[2] = f2bf(v0.z); o[3] = f2bf(v0.w);
        o[4] = f2bf(v1.x); o[5] = f2bf(v1.y); o[6] = f2bf(v1.z); o[7] = f2bf(v1.w);
        ((u16x8*)Oa)[i] = o;
    }
    for (size_t i = gid; i < nv8; i += stride) {
        float4 v0 = ((const float4*)B)[2 * i];
        float4 v1 = ((const float4*)B)[2 * i + 1];
        u16x8 o;
        o[0] = f2bf(v0.x); o[1] = f2bf(v0.y); o[2] = f2bf(v0.z); o[3] = f2bf(v0.w);
        o[4] = f2bf(v1.x); o[5] = f2bf(v1.y); o[6] = f2bf(v1.z); o[7] = f2bf(v1.w);
        ((u16x8*)Ob)[i] = o;
    }
}

// ---------- async global->LDS, 16B/lane, wave-uniform LDS base ----------
__device__ __forceinline__ void g2l16(const u16* g, u16* l) {
    __builtin_amdgcn_global_load_lds(
        (const __attribute__((address_space(1))) void*)g,
        (__attribute__((address_space(3))) void*)l,
        16, 0, 0);
}

// ---- LDS geometry (identical to round-2, verified 0 bank conflicts) ----
// 8 regions of 16 KB: {A,B} x {buf0,buf1} x {khalf0,khalf1}; region =
// 256 rows x 32 bf16. Row = 64 B = 4 chunks of 16 B; logical chunk c of
// row r stored at physical chunk c ^ ((r>>1)&3); inverse applied on the
// GLOBAL source chunk at staging.

__device__ __forceinline__ int frag_off(int row, int cbq) {
    return row * 32 + (cbq ^ ((row >> 1) & 3)) * 8;
}

// Phase p: issue ds_reads for phase p+1's fragments (register read-ahead),
// issue one region stage, barrier, MFMA on fragments loaded in phase p-1,
// vmcnt(4) (never 0), barrier. The compiler inserts the minimal counted
// lgkmcnt before the first consuming MFMA (C-level loads carry the dep), so
// phase p's LDS service burst overlaps phase p's MFMA burst.
#define PHASE(MH, ARn, AFW, DOB, BRn, BFW, AFR, BFR, SG, SL)                  \
  {                                                                           \
    _Pragma("unroll")                                                         \
    for (int i = 0; i < 4; ++i)                                               \
      (AFW)[i] = *(const s16x8*)&(ARn)[(MH) ? aoff0[i] : aoff1[i]];           \
    if (DOB) {                                                                \
      _Pragma("unroll")                                                       \
      for (int j = 0; j < 4; ++j)                                             \
        (BFW)[j] = *(const s16x8*)&(BRn)[boff[j]];                            \
    }                                                                         \
    g2l16((SG) + offR0, (SL) + wave * 512);                                   \
    g2l16((SG) + offR1, (SL) + (8 + wave) * 512);                             \
    __builtin_amdgcn_s_barrier();                                             \
    __builtin_amdgcn_s_setprio(1);                                            \
    _Pragma("unroll")                                                         \
    for (int i = 0; i < 4; ++i) {                                             \
      _Pragma("unroll")                                                       \
      for (int j = 0; j < 4; ++j)                                             \
        acc[(MH) * 4 + i][j] = __builtin_amdgcn_mfma_f32_16x16x32_bf16(       \
            (AFR)[i], (BFR)[j], acc[(MH) * 4 + i][j], 0, 0, 0);               \
    }                                                                         \
    __builtin_amdgcn_s_setprio(0);                                            \
    asm volatile("s_waitcnt vmcnt(4)");                                       \
    __builtin_amdgcn_s_barrier();                                             \
  }

// 256x256 macro-tile, BK=64, 8-phase read-ahead schedule, 512 threads.
// Region safety (2 loads staged/phase, vmcnt(4)/phase => a region staged at
// phase p is landed by end of phase p+2; earliest read-issue is p+4..p+5):
//   sA11@P0->rd P5 | sB11@P1->rd P5 | sA00@P2->rd P7 | sB00@P3->rd P7
//   sA01@P4->rd P1' | sB01@P5->rd P1' | sA10@P6->rd P3' | sB10@P7->rd P3'
// WAR (read-before-restage) margin >= 1 full phase for every region.
__global__ __launch_bounds__(512) void gemm_bt_bf16(
    const u16* __restrict__ A, const u16* __restrict__ B, float* __restrict__ C) {
    __shared__ __align__(16) u16 sm[65536];            // 128 KB
    u16* sA00 = sm;          u16* sA01 = sm + 8192;
    u16* sA10 = sm + 16384;  u16* sA11 = sm + 24576;
    u16* sB00 = sm + 32768;  u16* sB01 = sm + 40960;
    u16* sB10 = sm + 49152;  u16* sB11 = sm + 57344;

    const int tid   = threadIdx.x;
    const int lane  = tid & 63;
    const int wave  = tid >> 6;       // 0..7
    const int waveM = wave >> 2;      // 0..1
    const int waveN = wave & 3;       // 0..3
    const int fr    = lane & 15;
    const int cbq   = lane >> 4;

    // XCD-compact swizzle: 256 blocks, 16x16 tile grid.
    const int lin  = blockIdx.x;
    const int xcd  = lin & 7;
    const int j    = lin >> 3;
    const int tileY = (xcd >> 1) * 4 + (j & 3);
    const int tileX = (xcd & 1) * 8 + (j >> 2);
    const int rowBase = tileY * 256;
    const int colBase = tileX * 256;

    const u16* Abase = A + (size_t)rowBase * D_DIM;
    const u16* Bbase = B + (size_t)colBase * D_DIM;

    // Thread-invariant staging offsets (global source, inverse-swizzled chunk)
    const int s0 = wave * 64 + lane;
    const int s1 = (8 + wave) * 64 + lane;
    const size_t offR0 = (size_t)(s0 >> 2) * D_DIM + (size_t)(((s0 & 3) ^ ((s0 >> 3) & 3)) * 8);
    const size_t offR1 = (size_t)(s1 >> 2) * D_DIM + (size_t)(((s1 & 3) ^ ((s1 >> 3) & 3)) * 8);

    // Thread-invariant fragment read offsets (u16 units)
    int aoff0[4], aoff1[4], boff[4];
    #pragma unroll
    for (int i = 0; i < 4; ++i) {
        aoff0[i] = frag_off(waveM * 128 + i * 16 + fr, cbq);
        aoff1[i] = frag_off(waveM * 128 + (4 + i) * 16 + fr, cbq);
        boff[i]  = frag_off(waveN * 64 + i * 16 + fr, cbq);
    }

    f32x4 acc[8][4] = {};
    s16x8 af0[4], af1[4], bf0[4], bf1[4];

    // Prologue: stage 6 regions (12 loads/thread); vmcnt(4) -> first 4
    // regions landed, {sA10,sB10} (4 loads) in flight = steady-state entry.
    g2l16(Abase + offR0,      sA00 + wave * 512);
    g2l16(Abase + offR1,      sA00 + (8 + wave) * 512);
    g2l16(Bbase + offR0,      sB00 + wave * 512);
    g2l16(Bbase + offR1,      sB00 + (8 + wave) * 512);
    g2l16(Abase + 32 + offR0, sA01 + wave * 512);
    g2l16(Abase + 32 + offR1, sA01 + (8 + wave) * 512);
    g2l16(Bbase + 32 + offR0, sB01 + wave * 512);
    g2l16(Bbase + 32 + offR1, sB01 + (8 + wave) * 512);
    g2l16(Abase + 64 + offR0, sA10 + wave * 512);
    g2l16(Abase + 64 + offR1, sA10 + (8 + wave) * 512);
    g2l16(Bbase + 64 + offR0, sB10 + wave * 512);
    g2l16(Bbase + 64 + offR1, sB10 + (8 + wave) * 512);
    asm volatile("s_waitcnt vmcnt(4)");
    __builtin_amdgcn_s_barrier();

    // Preload phase-0 fragments (sA00/sB00 are landed).
    #pragma unroll
    for (int i = 0; i < 4; ++i) af0[i] = *(const s16x8*)&sA00[aoff0[i]];
    #pragma unroll
    for (int i = 0; i < 4; ++i) bf0[i] = *(const s16x8*)&sB00[boff[i]];

    #pragma unroll 1
    for (int t = 0; t < 64; t += 2) {
        const int t2 = (t + 2 < 64) ? t + 2 : 62;  // clamped tail re-stage
        const int t3 = (t + 3 < 64) ? t + 3 : 62;  // (written, never consumed)
        const u16* As1 = Abase + (t + 1) * 64;
        const u16* Bs1 = Bbase + (t + 1) * 64;
        const u16* As2 = Abase + t2 * 64;
        const u16* Bs2 = Bbase + t2 * 64;
        const u16* As3 = Abase + t3 * 64;
        const u16* Bs3 = Bbase + t3 * 64;

        //    MH  ARn   AFW  DOB BRn   BFW  AFR  BFR  SG        SL
        PHASE(0,  sA00, af1, 0,  sB00, bf1, af0, bf0, As1 + 32, sA11)
        PHASE(1,  sA01, af0, 1,  sB01, bf1, af1, bf0, Bs1 + 32, sB11)
        PHASE(0,  sA01, af1, 0,  sB01, bf1, af0, bf1, As2,      sA00)
        PHASE(1,  sA10, af0, 1,  sB10, bf0, af1, bf1, Bs2,      sB00)
        PHASE(0,  sA10, af1, 0,  sB10, bf0, af0, bf0, As2 + 32, sA01)
        PHASE(1,  sA11, af0, 1,  sB11, bf1, af1, bf0, Bs2 + 32, sB01)
        PHASE(0,  sA11, af1, 0,  sB11, bf1, af0, bf1, As3,      sA10)
        PHASE(1,  sA00, af0, 1,  sB00, bf0, af1, bf1, Bs3,      sB10)
    }

    // Epilogue. C/D layout (verified m89/m91): col = lane&15, row = (lane>>4)*4 + reg
    #pragma unroll
    for (int mt = 0; mt < 8; ++mt) {
        int gr0 = rowBase + waveM * 128 + mt * 16 + (lane >> 4) * 4;
        #pragma unroll
        for (int nt = 0; nt < 4; ++nt) {
            int gc = colBase + waveN * 64 + nt * 16 + (lane & 15);
            #pragma unroll
            for (int r = 0; r < 4; ++r)
                C[(size_t)(gr0 + r) * M_DIM + gc] = acc[mt][nt][r];
        }
    }
}

extern "C" void kernel_launch(void* const* d_in, const int* in_sizes, int n_in,
                              void* d_out, int out_size, void* d_ws, size_t ws_size,
                              hipStream_t stream) {
    const float* A32 = (const float*)d_in[0];
    const float* B32 = (const float*)d_in[1];
    float* C = (float*)d_out;

    u16* Abf = (u16*)d_ws;
    u16* Bbf = Abf + (size_t)N_DIM * D_DIM;

    convert_both<<<4096, 256, 0, stream>>>(A32, B32, Abf, Bbf);
    gemm_bt_bf16<<<256, 512, 0, stream>>>(Abf, Bbf, C);
}